// Round 1
// baseline (237.801 us; speedup 1.0000x reference)
//
#include <hip/hip_runtime.h>
#include <stdint.h>

// ListwiseLoss: B=524288 rows, H=32.
// Per row: m = mask & (rankings>0); p = softmax(where(m, scores, -1e9));
// kl = sum_valid p*log(p) - sum_j p[rank_order_j]*log(p[index_order_j]+1e-8)
// out = mean of kl over rows with n_valid > 1.
//
// Layout: 32 lanes per row, 2 rows per wave64. j_pos via popcount of valid
// mask; j_rank via 5-bit bitwise radix rank (rankings of valid entries are
// 1..32 -> r-1 fits 5 bits); stable tie-break from the surviving match mask.
// Pairing q_j <-> pr_j via ds_permute scatter (by j_pos) + ds_bpermute
// gather (by j_rank), no LDS arrays.

__global__ __launch_bounds__(256) void listwise_kernel(
    const float* __restrict__ scores,
    const int* __restrict__ rankings,
    const unsigned char* __restrict__ mask_u8,
    float* __restrict__ ws_kl,
    int* __restrict__ ws_cnt,
    int npairs)
{
    const int lane = threadIdx.x & 63;
    const int gl   = lane & 31;          // lane within 32-lane row group
    const int sh   = lane & 32;          // 0 for lanes 0-31, 32 for 32-63
    const uint32_t lmask = (1u << gl) - 1u;  // lanes below me in group
    const int wid = threadIdx.x >> 6;
    const int wavesPerBlock = blockDim.x >> 6;
    const int gw = blockIdx.x * wavesPerBlock + wid;
    const int totWaves = gridDim.x * wavesPerBlock;

    // Detect mask element width (bool=1B vs int32=4B). int32 layout of 0/1
    // values has all bytes at offset%4!=0 equal to zero; random bool bytes
    // trip this with prob 2^-48. Wave-uniform -> cheap branch.
    unsigned char probe = mask_u8[lane];
    const bool mask_is_i32 =
        (__ballot(((lane & 3) != 0) && (probe != 0)) == 0ull);
    const int* mask_i32 = (const int*)mask_u8;

    float th_kl = 0.0f;
    int   th_cnt = 0;

    for (int pair = gw; pair < npairs; pair += totWaves) {
        const int base = pair * 64 + lane;   // 64 consecutive elems = 2 rows
        const float s = scores[base];
        const int   r = rankings[base];
        const int   mk = mask_is_i32 ? mask_i32[base] : (int)mask_u8[base];
        const bool valid = (mk != 0) && (r > 0);

        const unsigned long long balv = __ballot(valid);
        const uint32_t vm = (uint32_t)(balv >> sh);   // group valid mask
        const int nv = __popc(vm);

        // ---- softmax over the 32-lane group (masks<32 never cross groups)
        float x = valid ? s : -3.0e38f;
        #pragma unroll
        for (int m = 16; m >= 1; m >>= 1) x = fmaxf(x, __shfl_xor(x, m));
        const float e = valid ? __expf(s - x) : 0.0f;
        float se = e;
        #pragma unroll
        for (int m = 16; m >= 1; m >>= 1) se += __shfl_xor(se, m);
        const float p = e / se;              // 0 at invalid (when nv>0)
        const float lp1 = __logf(p);         // log(q)
        const float lp2 = __logf(p + 1e-8f); // log(pr + eps)

        // ---- rank position: #{valid k: (r_k, k) < (r_me, me)}  (stable)
        const uint32_t v = ((uint32_t)(r - 1)) & 31u;  // 5-bit key, garbage ok if !valid
        uint32_t E = vm;      // candidates matching my high bits so far
        int c_lt = 0;
        #pragma unroll
        for (int i = 4; i >= 0; --i) {
            const unsigned long long bb = __ballot((v >> i) & 1u);
            const uint32_t bi = (uint32_t)(bb >> sh);
            const uint32_t t = (v >> i) & 1u;
            c_lt += t ? __popc(E & ~bi) : 0;
            E &= t ? bi : ~bi;
        }
        // E now = valid lanes with ranking == mine
        const int eq_below = __popc(E & lmask);
        const int j_rank = c_lt + eq_below;
        const int j_pos  = __popc(vm & lmask);

        // ---- pair q_j with pr_j: scatter lp2 to slot j_pos, gather at j_rank.
        // Invalid lanes get distinct parking slots [nv,32) so no push conflicts.
        const int inv_pos = gl - j_pos;
        const int dst = valid ? j_pos : (nv + inv_pos);
        const int scat = __builtin_amdgcn_ds_permute((sh + dst) << 2,
                                                     __float_as_int(lp2));
        const int gidx = valid ? j_rank : 0;
        const float g = __int_as_float(
            __builtin_amdgcn_ds_bpermute((sh + gidx) << 2, scat));

        float term = valid ? p * (lp1 - g) : 0.0f;
        #pragma unroll
        for (int m = 16; m >= 1; m >>= 1) term += __shfl_xor(term, m);

        if (gl == 0 && nv > 1) { th_kl += term; th_cnt += 1; }
    }

    // ---- block reduction, one atomic pair per block
    #pragma unroll
    for (int m = 32; m >= 1; m >>= 1) {
        th_kl  += __shfl_xor(th_kl, m);
        th_cnt += __shfl_xor(th_cnt, m);
    }
    __shared__ float s_kl[8];
    __shared__ int   s_cnt[8];
    if (lane == 0) { s_kl[wid] = th_kl; s_cnt[wid] = th_cnt; }
    __syncthreads();
    if (threadIdx.x == 0) {
        float k = 0.0f; int c = 0;
        for (int i = 0; i < wavesPerBlock; ++i) { k += s_kl[i]; c += s_cnt[i]; }
        atomicAdd(ws_kl, k);
        atomicAdd(ws_cnt, c);
    }
}

__global__ void finalize_kernel(const float* __restrict__ ws_kl,
                                const int* __restrict__ ws_cnt,
                                float* __restrict__ out)
{
    if (threadIdx.x == 0) {
        int c = *ws_cnt;
        if (c < 1) c = 1;
        out[0] = *ws_kl / (float)c;
    }
}

extern "C" void kernel_launch(void* const* d_in, const int* in_sizes, int n_in,
                              void* d_out, int out_size, void* d_ws, size_t ws_size,
                              hipStream_t stream) {
    const float* scores = (const float*)d_in[0];
    const int* rankings = (const int*)d_in[1];
    const unsigned char* mask = (const unsigned char*)d_in[2];
    float* out = (float*)d_out;

    const int total = in_sizes[0];       // B*H = 16777216
    const int npairs = total / 64;       // 2 rows (64 elems) per wave

    float* wsf = (float*)d_ws;           // [0]: kl sum (float)
    int*   wsi = (int*)d_ws;             // [1]: row count (int)

    hipMemsetAsync(d_ws, 0, 8, stream);

    const int threads = 256;
    const int blocks = 2048;             // grid-stride; 2 atomics per block
    listwise_kernel<<<blocks, threads, 0, stream>>>(
        scores, rankings, mask, wsf, wsi + 1, npairs);

    finalize_kernel<<<1, 64, 0, stream>>>(wsf, wsi + 1, out);
}